// Round 5
// baseline (271.151 us; speedup 1.0000x reference)
//
#include <hip/hip_runtime.h>
#include <cstdint>
#include <cstddef>

#define NUM_C 21
#define NROW 336      // 21 classes * 16 images, row r = cls*16 + img
#define N2   (NROW * NROW)
#define KSLABS 16     // k2 K-split: 16 slabs of 256 pixels

typedef __attribute__((ext_vector_type(8))) short short8;   // 8 bf16 = 4 VGPRs (MFMA A/B frag)
typedef __attribute__((ext_vector_type(4))) float f32x4;
typedef __attribute__((ext_vector_type(16))) float f32x16;  // 32x32 MFMA C/D frag
typedef __attribute__((ext_vector_type(4))) int int4v;

union frag_u { int4v i; short8 s; };
__device__ __forceinline__ short8 mk_frag(uint32_t a0, uint32_t a1, uint32_t a2, uint32_t a3) {
    frag_u u; u.i = int4v{(int)a0, (int)a1, (int)a2, (int)a3}; return u.s;
}
// packed bf16x2 one-hot: low16 = (eL==c), high16 = (eH==c), value 1.0bf16/0
__device__ __forceinline__ uint32_t mask_pair(uint32_t eL, uint32_t eH, uint32_t c) {
    return (eL == c ? 0x3F80u : 0u) | (eH == c ? 0x3F800000u : 0u);
}

// ---------------- K1: bilinear label resize (513x513 -> 64x64) + per-block histogram ----
// NT label reads (round-4: NT on streaming readers won 12us total).
__global__ __launch_bounds__(256) void k1_resize_hist(const int* __restrict__ labels,
                                                      uint8_t* __restrict__ lab,
                                                      int* __restrict__ countsPart,
                                                      float* __restrict__ out) {
    int b = blockIdx.x >> 4, strip = blockIdx.x & 15;
    if (blockIdx.x == 0 && threadIdx.x == 0) out[0] = 0.0f;  // K5 (later in stream) accumulates
    __shared__ int hist[NUM_C];
    if (threadIdx.x < NUM_C) hist[threadIdx.x] = 0;
    __syncthreads();

    int p = strip * 256 + threadIdx.x;      // pixel in [0,4096)
    int y = p >> 6, x = p & 63;
    const int* L = labels + (size_t)b * 263169;   // 513*513
    // sample_f = (i+0.5)*513/64 - 0.5 ; 513/64 = 8.015625 exact in fp32; range [3.5,508.5] -> no clamp
    float sy = (y + 0.5f) * 8.015625f - 0.5f;
    float sx = (x + 0.5f) * 8.015625f - 0.5f;
    int y0 = (int)sy; float fy = sy - (float)y0;
    int x0 = (int)sx; float fx = sx - (float)x0;
    const int* r0 = L + y0 * 513 + x0;
    float L00 = (float)__builtin_nontemporal_load(r0);
    float L01 = (float)__builtin_nontemporal_load(r0 + 1);
    float L10 = (float)__builtin_nontemporal_load(r0 + 513);
    float L11 = (float)__builtin_nontemporal_load(r0 + 514);
    float v0 = (1.0f - fx) * L00 + fx * L01;
    float v1 = (1.0f - fx) * L10 + fx * L11;
    float val = (1.0f - fy) * v0 + fy * v1;
    int c = (int)val;
    lab[b * 4096 + p] = (uint8_t)c;
    atomicAdd(&hist[c], 1);
    __syncthreads();
    if (threadIdx.x < NUM_C) countsPart[blockIdx.x * NUM_C + threadIdx.x] = hist[threadIdx.x];
}

// ---------------- K2: masked pooling as ONE-TILE 32x32x16 MFMA GEMM ---------------------
// Round-4 post-mortem: k2 stuck ~2x over stream floor; inner loop was latency/issue-bound:
// (1) two 16x16 mask tiles = ~112 VALU per 2KB before next loads could issue;
// (2) per-lane loads were 32B islands strided 128B (k-group interleave) -> address VALU +
//     weak load batching.
// This version:
//  - 32x32x16 mfma: 21 classes fit ONE A-tile (rows 21..31 auto-zero) -> mask VALU and
//    MFMA count per 2KB both halve; no second-tile epilogue.
//  - PERMUTED-K pixel map (GEMM K-order is free by associativity): step s, k-group g,
//    elem j -> pixel g*128 + s*8 + j. Each lane's 16 steps read ONE contiguous 512B
//    stretch -> all loads are base+imm-offset, compiler batches them 8 deep.
//    Masks use the SAME map, so any HW k-permutation cancels (A,B share convention).
//  - A-frag labels: all 32 lanes of a k-group read the same 8B -> broadcast load.
// Layouts (verified m74/m101): A row = lane&31 (=class), B col = lane&31 (=d),
// k = (lane>>5)*8 + j; C/D col = lane&31, row = (reg&3) + 8*(reg>>2) + 4*(lane>>5).
// fp32 -> bf16 hi + bf16 lo residual (exact subtraction), fp32 accumulate: absmax was 0.0.
__global__ __launch_bounds__(256, 4) void k2_sums(const float* __restrict__ feat,
                                                  const uint8_t* __restrict__ lab,
                                                  float* __restrict__ sums_part) {
    int bid = blockIdx.x;                 // 1024 = b(16) x slab(16) x ng(4)
    int b = bid >> 6, slab = (bid >> 2) & 15, ng = bid & 3;
    int t = threadIdx.x, wv = t >> 6, lane = t & 63;
    int g = lane >> 5;                    // k-group (0,1)
    int dbase = (ng * 4 + wv) * 32;
    int d = dbase + (lane & 31);
    uint32_t c = lane & 31;               // A row = class (>=21 -> mask always 0)
    const float*   fp = feat + ((size_t)(b * 512 + d)) * 4096 + slab * 256 + g * 128;
    const uint8_t* lp = lab + b * 4096 + slab * 256 + g * 128;

    f32x16 acc;
#pragma unroll
    for (int j = 0; j < 16; ++j) acc[j] = 0.0f;

#pragma unroll 4
    for (int s = 0; s < 16; ++s) {        // 16 steps x K=16 px = 256 px
        f32x4 fA = __builtin_nontemporal_load((const f32x4*)(fp + s * 8));
        f32x4 fB = __builtin_nontemporal_load((const f32x4*)(fp + s * 8 + 4));
        uint32_t w0 = *(const uint32_t*)(lp + s * 8);      // wave-uniform per k-group
        uint32_t w1 = *(const uint32_t*)(lp + s * 8 + 4);  // (broadcast); labels cached

        uint32_t u0 = __float_as_uint(fA[0]), u1 = __float_as_uint(fA[1]),
                 u2 = __float_as_uint(fA[2]), u3 = __float_as_uint(fA[3]),
                 u4 = __float_as_uint(fB[0]), u5 = __float_as_uint(fB[1]),
                 u6 = __float_as_uint(fB[2]), u7 = __float_as_uint(fB[3]);
        // hi = truncate-to-bf16: pack high16 of consecutive floats (1 v_perm per pair)
        short8 bHi = mk_frag(__builtin_amdgcn_perm(u1, u0, 0x07060302u),
                             __builtin_amdgcn_perm(u3, u2, 0x07060302u),
                             __builtin_amdgcn_perm(u5, u4, 0x07060302u),
                             __builtin_amdgcn_perm(u7, u6, 0x07060302u));
        // lo = truncate-to-bf16 of exact residual f - hi (shared exponent -> exact)
        float t0 = fA[0] - __uint_as_float(u0 & 0xFFFF0000u);
        float t1 = fA[1] - __uint_as_float(u1 & 0xFFFF0000u);
        float t2 = fA[2] - __uint_as_float(u2 & 0xFFFF0000u);
        float t3 = fA[3] - __uint_as_float(u3 & 0xFFFF0000u);
        float t4 = fB[0] - __uint_as_float(u4 & 0xFFFF0000u);
        float t5 = fB[1] - __uint_as_float(u5 & 0xFFFF0000u);
        float t6 = fB[2] - __uint_as_float(u6 & 0xFFFF0000u);
        float t7 = fB[3] - __uint_as_float(u7 & 0xFFFF0000u);
        short8 bLo = mk_frag(
            __builtin_amdgcn_perm(__float_as_uint(t1), __float_as_uint(t0), 0x07060302u),
            __builtin_amdgcn_perm(__float_as_uint(t3), __float_as_uint(t2), 0x07060302u),
            __builtin_amdgcn_perm(__float_as_uint(t5), __float_as_uint(t4), 0x07060302u),
            __builtin_amdgcn_perm(__float_as_uint(t7), __float_as_uint(t6), 0x07060302u));

        uint32_t e0 = w0 & 255u, e1 = (w0 >> 8) & 255u, e2 = (w0 >> 16) & 255u, e3 = w0 >> 24;
        uint32_t e4 = w1 & 255u, e5 = (w1 >> 8) & 255u, e6 = (w1 >> 16) & 255u, e7 = w1 >> 24;
        short8 a = mk_frag(mask_pair(e0, e1, c), mask_pair(e2, e3, c),
                           mask_pair(e4, e5, c), mask_pair(e6, e7, c));

        acc = __builtin_amdgcn_mfma_f32_32x32x16_bf16(a, bHi, acc, 0, 0, 0);
        acc = __builtin_amdgcn_mfma_f32_32x32x16_bf16(a, bLo, acc, 0, 0, 0);
    }

    // C/D: col = lane&31 (=d), row = (j&3) + 8*(j>>2) + 4*(lane>>5) (=class).
    // Per (j, half): 32 lanes write 128B consecutive -> coalesced.
    float* sp = sums_part + (size_t)slab * NROW * 512;
    int rb = 4 * g;
#pragma unroll
    for (int j = 0; j < 16; ++j) {
        int row = (j & 3) + 8 * (j >> 2) + rb;
        if (row < NUM_C) sp[(size_t)(row * 16 + b) * 512 + d] = acc[j];
    }
}

// ---------------- K3: fold 16 k-slab partials -> sums[336][512] -------------------------
// Reads its own just-written 11MB (L2/L3-warm): keep cached loads.
__global__ __launch_bounds__(256) void k3_fold(const float4* __restrict__ part,
                                               float4* __restrict__ sums) {
    int idx = blockIdx.x * 256 + threadIdx.x;   // 43008 float4s = 336*512 floats
    float4 s = part[idx];
#pragma unroll
    for (int q = 1; q < KSLABS; ++q) {
        float4 v = part[q * 43008 + idx];
        s.x += v.x; s.y += v.y; s.z += v.z; s.w += v.w;
    }
    sums[idx] = s;
}

// ---------------- K4: Gram of folded sums, k-split into 8 partial slabs -----------------
__global__ __launch_bounds__(64) void k4_gram(const float* __restrict__ sums,
                                              float* __restrict__ gpart) {
    int row0 = blockIdx.x * 32, col0 = blockIdx.y * 32, k0 = blockIdx.z * 64;
    __shared__ float A[32 * 66], Bt[32 * 66];
    int t = threadIdx.x;
    int row = t >> 1, kk0 = (t & 1) * 32;
#pragma unroll
    for (int q = 0; q < 8; ++q) {
        int kk = kk0 + q * 4;
        int ra = row0 + row, rb = col0 + row;
        float4 va = (ra < NROW) ? *(const float4*)&sums[(size_t)ra * 512 + k0 + kk]
                                : make_float4(0.f, 0.f, 0.f, 0.f);
        float4 vb = (rb < NROW) ? *(const float4*)&sums[(size_t)rb * 512 + k0 + kk]
                                : make_float4(0.f, 0.f, 0.f, 0.f);
        *(float2*)&A[row * 66 + kk]      = make_float2(va.x, va.y);
        *(float2*)&A[row * 66 + kk + 2]  = make_float2(va.z, va.w);
        *(float2*)&Bt[row * 66 + kk]     = make_float2(vb.x, vb.y);
        *(float2*)&Bt[row * 66 + kk + 2] = make_float2(vb.z, vb.w);
    }
    __syncthreads();
    int ty = t >> 3, tx = t & 7;
    float acc[4][4] = {};
    for (int kk = 0; kk < 64; kk += 2) {
        float2 a[4], bb[4];
#pragma unroll
        for (int u = 0; u < 4; ++u) {
            a[u]  = *(const float2*)&A[(ty * 4 + u) * 66 + kk];
            bb[u] = *(const float2*)&Bt[(tx * 4 + u) * 66 + kk];
        }
#pragma unroll
        for (int u = 0; u < 4; ++u)
#pragma unroll
            for (int v = 0; v < 4; ++v)
                acc[u][v] += a[u].x * bb[v].x + a[u].y * bb[v].y;
    }
    float* gp = gpart + (size_t)blockIdx.z * N2;
#pragma unroll
    for (int u = 0; u < 4; ++u) {
        int r1 = row0 + ty * 4 + u;
        if (r1 >= NROW) continue;
        int r2 = col0 + tx * 4;
        if (r2 + 3 < NROW) {
            *(float4*)&gp[(size_t)r1 * NROW + r2] =
                make_float4(acc[u][0], acc[u][1], acc[u][2], acc[u][3]);
        } else {
#pragma unroll
            for (int v = 0; v < 4; ++v)
                if (r2 + v < NROW) gp[(size_t)r1 * NROW + r2 + v] = acc[u][v];
        }
    }
}

// ---------------- K5: per-class masked LSE loss, single pass ----------------------------
__global__ __launch_bounds__(1024) void k5_loss(const float* __restrict__ gpart,
                                                const int* __restrict__ countsPart,
                                                float* __restrict__ out) {
    int c = blockIdx.x, t = threadIdx.x;
    int wv = t >> 6, lane = t & 63;
    __shared__ float invnL[NROW];
    __shared__ uint8_t presL[NROW];
    __shared__ float redE[16], redD[16], redL[16];

    for (int r = t; r < NROW; r += 1024) {
        float ss = 0.0f;
#pragma unroll
        for (int s = 0; s < 8; ++s) ss += gpart[(size_t)s * N2 + (size_t)r * 337];
        invnL[r] = 1.0f / fmaxf(sqrtf(ss), 1e-12f);
        int img = r & 15, cls = r >> 4;
        int cnt = 0;
#pragma unroll
        for (int s = 0; s < 16; ++s) cnt += countsPart[(img * 16 + s) * NUM_C + cls];
        presL[r] = cnt > 0 ? 1 : 0;
    }
    __syncthreads();

    int nc = 0;
#pragma unroll
    for (int j = 0; j < 16; ++j) nc += presL[c * 16 + j];
    if (nc == 0) return;   // class absent in all images: contributes 0 (uniform exit)

    float eS = 0.0f, dE = 0.0f, dL = 0.0f;
    for (int idx = t; idx < 16 * NROW; idx += 1024) {
        int i = idx / NROW, r2 = idx - i * NROW;
        int r1 = c * 16 + i;
        float g = 0.0f;
#pragma unroll
        for (int s = 0; s < 8; ++s) g += gpart[(size_t)s * N2 + (size_t)r1 * NROW + r2];
        if (presL[r1] && presL[r2]) {
            float sv = g * invnL[r1] * invnL[r2] * 10.0f;   // /T, T=0.1
            float e = expf(sv - 10.0f);
            eS += e;
            if ((r2 >> 4) == c) { dE += e; dL += sv; }      // diag block (appears twice)
        }
    }
#pragma unroll
    for (int off = 32; off >= 1; off >>= 1) {
        eS += __shfl_xor(eS, off, 64);
        dE += __shfl_xor(dE, off, 64);
        dL += __shfl_xor(dL, off, 64);
    }
    if (lane == 0) { redE[wv] = eS; redD[wv] = dE; redL[wv] = dL; }
    __syncthreads();
    if (t == 0) {
        float E = 0, D = 0, Ln = 0;
#pragma unroll
        for (int w = 0; w < 16; ++w) { E += redE[w]; D += redD[w]; Ln += redL[w]; }
        float lse = 10.0f + logf(E + D);
        float posMean = Ln / (float)(nc * nc);
        atomicAdd(out, lse - posMean);
    }
}

// ---------------- launcher --------------------------------------------------------------
extern "C" void kernel_launch(void* const* d_in, const int* in_sizes, int n_in,
                              void* d_out, int out_size, void* d_ws, size_t ws_size,
                              hipStream_t stream) {
    const float* features = (const float*)d_in[0];
    const int* labels = (const int*)d_in[1];
    char* ws = (char*)d_ws;

    uint8_t* lab     = (uint8_t*)ws;                               // 65536 B
    int* countsPart  = (int*)(ws + 65536);                         // 21504 B
    float* sums_part = (float*)(ws + 87040);                       // 16*336*512*4 = 11010048 B
    float* sums      = (float*)(ws + 87040 + 11010048);            // 688128 B
    float* gpart     = (float*)(ws + 87040 + 11010048 + 688128);   // 3612672 B
    float* out       = (float*)d_out;

    k1_resize_hist<<<256, 256, 0, stream>>>(labels, lab, countsPart, out);
    k2_sums<<<1024, 256, 0, stream>>>(features, lab, sums_part);
    k3_fold<<<168, 256, 0, stream>>>((const float4*)sums_part, (float4*)sums);
    k4_gram<<<dim3(11, 11, 8), 64, 0, stream>>>(sums, gpart);
    k5_loss<<<21, 1024, 0, stream>>>(gpart, countsPart, out);
}

// Round 6
// 243.460 us; speedup vs baseline: 1.1137x; 1.1137x over previous
//
#include <hip/hip_runtime.h>
#include <cstdint>
#include <cstddef>

#define NUM_C 21
#define NROW 336      // 21 classes * 16 images, row r = cls*16 + img
#define N2   (NROW * NROW)
#define KSLABS 32     // k2 K-split: 32 slabs of 128 pixels

typedef __attribute__((ext_vector_type(8))) short short8;   // 8 bf16 = 4 VGPRs (MFMA A/B frag)
typedef __attribute__((ext_vector_type(4))) float f32x4;
typedef __attribute__((ext_vector_type(16))) float f32x16;  // 32x32 MFMA C/D frag
typedef __attribute__((ext_vector_type(4))) int int4v;

union frag_u { int4v i; short8 s; };
__device__ __forceinline__ short8 mk_frag(uint32_t a0, uint32_t a1, uint32_t a2, uint32_t a3) {
    frag_u u; u.i = int4v{(int)a0, (int)a1, (int)a2, (int)a3}; return u.s;
}
// packed bf16x2 one-hot: low16 = (eL==c), high16 = (eH==c), value 1.0bf16/0
__device__ __forceinline__ uint32_t mask_pair(uint32_t eL, uint32_t eH, uint32_t c) {
    return (eL == c ? 0x3F80u : 0u) | (eH == c ? 0x3F800000u : 0u);
}

// ---------------- K1: bilinear label resize (513x513 -> 64x64) + per-block histogram ----
__global__ __launch_bounds__(256) void k1_resize_hist(const int* __restrict__ labels,
                                                      uint8_t* __restrict__ lab,
                                                      int* __restrict__ countsPart,
                                                      float* __restrict__ out) {
    int b = blockIdx.x >> 4, strip = blockIdx.x & 15;
    if (blockIdx.x == 0 && threadIdx.x == 0) out[0] = 0.0f;  // K5 (later in stream) accumulates
    __shared__ int hist[NUM_C];
    if (threadIdx.x < NUM_C) hist[threadIdx.x] = 0;
    __syncthreads();

    int p = strip * 256 + threadIdx.x;      // pixel in [0,4096)
    int y = p >> 6, x = p & 63;
    const int* L = labels + (size_t)b * 263169;   // 513*513
    // sample_f = (i+0.5)*513/64 - 0.5 ; 513/64 = 8.015625 exact in fp32; range [3.5,508.5] -> no clamp
    float sy = (y + 0.5f) * 8.015625f - 0.5f;
    float sx = (x + 0.5f) * 8.015625f - 0.5f;
    int y0 = (int)sy; float fy = sy - (float)y0;
    int x0 = (int)sx; float fx = sx - (float)x0;
    const int* r0 = L + y0 * 513 + x0;
    float L00 = (float)__builtin_nontemporal_load(r0);
    float L01 = (float)__builtin_nontemporal_load(r0 + 1);
    float L10 = (float)__builtin_nontemporal_load(r0 + 513);
    float L11 = (float)__builtin_nontemporal_load(r0 + 514);
    float v0 = (1.0f - fx) * L00 + fx * L01;
    float v1 = (1.0f - fx) * L10 + fx * L11;
    float val = (1.0f - fy) * v0 + fy * v1;
    int c = (int)val;
    lab[b * 4096 + p] = (uint8_t)c;
    atomicAdd(&hist[c], 1);
    __syncthreads();
    if (threadIdx.x < NUM_C) countsPart[blockIdx.x * NUM_C + threadIdx.x] = hist[threadIdx.x];
}

// ---------------- K2: masked pooling as ONE-TILE 32x32x16 MFMA GEMM ---------------------
// Round-5 counters: 84us, BW 2.2TB/s, Occ 27%, FETCH 170MB (134 ideal) -> latency-bound
// (too few waves in flight) + NT refetch (steps consumed only half of each 64B line).
// Fixes here:
//  - pixel map p = s*32 + u*16 + g*8 + j (u=0,1): per u-chunk the wave's two g-halves
//    consume each 64B line COMPLETELY within one fA/fB pair -> no NT refetch, 32
//    lines/instr.
//  - 32 slabs x 2048 blocks = 8 blocks/CU; __launch_bounds__(256,8) caps VGPR at 64
//    -> 32 waves/CU (2x round 5's MLP).
//  - explicit 1-deep software pipeline over the 8 u-chunks (static indices only):
//    chunk i+1's 2 feature loads + label load issue before chunk i's pack/mask VALU.
// Layouts (verified r5, absmax 0.0): A row = lane&31 (=class, >=21 auto-zero),
// B col = lane&31 (=d), k = g*8+j; C/D col = lane&31, row = (j&3)+8*(j>>2)+4*g.
// fp32 -> bf16 hi + exact-residual lo, fp32 accumulate.
__global__ __launch_bounds__(256, 8) void k2_sums(const float* __restrict__ feat,
                                                  const uint8_t* __restrict__ lab,
                                                  float* __restrict__ sums_part) {
    int bid = blockIdx.x;                 // 2048 = b(16) x slab(32) x ng(4)
    int b = bid >> 7, slab = (bid >> 2) & 31, ng = bid & 3;
    int t = threadIdx.x, wv = t >> 6, lane = t & 63;
    int g = lane >> 5;                    // k-group (0,1)
    int d = (ng * 4 + wv) * 32 + (lane & 31);
    uint32_t c = lane & 31;               // A row = class (>=21 -> mask always 0)
    const float*   fp = feat + ((size_t)(b * 512 + d)) * 4096 + slab * 128 + g * 8;
    const uint8_t* lp = lab + b * 4096 + slab * 128 + g * 8;

    f32x16 acc;
#pragma unroll
    for (int j = 0; j < 16; ++j) acc[j] = 0.0f;

    // u-chunk i (i = 0..7) reads floats [i*16 + 0..8) via fA,fB; labels 8B at lp + i*16.
    f32x4 fa_n = __builtin_nontemporal_load((const f32x4*)(fp));
    f32x4 fb_n = __builtin_nontemporal_load((const f32x4*)(fp + 4));
    uint2 w_n  = *(const uint2*)(lp);

#pragma unroll
    for (int i = 0; i < 8; ++i) {
        f32x4 fA = fa_n, fB = fb_n; uint2 wl = w_n;
        if (i < 7) {   // prefetch next chunk (static offsets; in flight during VALU below)
            fa_n = __builtin_nontemporal_load((const f32x4*)(fp + (i + 1) * 16));
            fb_n = __builtin_nontemporal_load((const f32x4*)(fp + (i + 1) * 16 + 4));
            w_n  = *(const uint2*)(lp + (i + 1) * 16);
        }

        uint32_t u0 = __float_as_uint(fA[0]), u1 = __float_as_uint(fA[1]),
                 u2 = __float_as_uint(fA[2]), u3 = __float_as_uint(fA[3]),
                 u4 = __float_as_uint(fB[0]), u5 = __float_as_uint(fB[1]),
                 u6 = __float_as_uint(fB[2]), u7 = __float_as_uint(fB[3]);
        // hi = truncate-to-bf16: pack high16 of consecutive floats (1 v_perm per pair)
        short8 bHi = mk_frag(__builtin_amdgcn_perm(u1, u0, 0x07060302u),
                             __builtin_amdgcn_perm(u3, u2, 0x07060302u),
                             __builtin_amdgcn_perm(u5, u4, 0x07060302u),
                             __builtin_amdgcn_perm(u7, u6, 0x07060302u));
        // lo = truncate-to-bf16 of exact residual f - hi (shared exponent -> exact)
        float t0 = fA[0] - __uint_as_float(u0 & 0xFFFF0000u);
        float t1 = fA[1] - __uint_as_float(u1 & 0xFFFF0000u);
        float t2 = fA[2] - __uint_as_float(u2 & 0xFFFF0000u);
        float t3 = fA[3] - __uint_as_float(u3 & 0xFFFF0000u);
        float t4 = fB[0] - __uint_as_float(u4 & 0xFFFF0000u);
        float t5 = fB[1] - __uint_as_float(u5 & 0xFFFF0000u);
        float t6 = fB[2] - __uint_as_float(u6 & 0xFFFF0000u);
        float t7 = fB[3] - __uint_as_float(u7 & 0xFFFF0000u);
        short8 bLo = mk_frag(
            __builtin_amdgcn_perm(__float_as_uint(t1), __float_as_uint(t0), 0x07060302u),
            __builtin_amdgcn_perm(__float_as_uint(t3), __float_as_uint(t2), 0x07060302u),
            __builtin_amdgcn_perm(__float_as_uint(t5), __float_as_uint(t4), 0x07060302u),
            __builtin_amdgcn_perm(__float_as_uint(t7), __float_as_uint(t6), 0x07060302u));

        uint32_t e0 = wl.x & 255u, e1 = (wl.x >> 8) & 255u,
                 e2 = (wl.x >> 16) & 255u, e3 = wl.x >> 24;
        uint32_t e4 = wl.y & 255u, e5 = (wl.y >> 8) & 255u,
                 e6 = (wl.y >> 16) & 255u, e7 = wl.y >> 24;
        short8 a = mk_frag(mask_pair(e0, e1, c), mask_pair(e2, e3, c),
                           mask_pair(e4, e5, c), mask_pair(e6, e7, c));

        acc = __builtin_amdgcn_mfma_f32_32x32x16_bf16(a, bHi, acc, 0, 0, 0);
        acc = __builtin_amdgcn_mfma_f32_32x32x16_bf16(a, bLo, acc, 0, 0, 0);
    }

    // C/D: col = lane&31 (=d), row = (j&3) + 8*(j>>2) + 4*g (=class).
    // Per (j): 32 lanes write 128B consecutive -> coalesced.
    float* sp = sums_part + (size_t)slab * NROW * 512;
    int rb = 4 * g;
#pragma unroll
    for (int j = 0; j < 16; ++j) {
        int row = (j & 3) + 8 * (j >> 2) + rb;
        if (row < NUM_C) sp[(size_t)(row * 16 + b) * 512 + d] = acc[j];
    }
}

// ---------------- K3: fold 32 k-slab partials -> sums[336][512] -------------------------
// Reads its own just-written 22MB (L2/L3-warm): keep cached loads.
__global__ __launch_bounds__(256) void k3_fold(const float4* __restrict__ part,
                                               float4* __restrict__ sums) {
    int idx = blockIdx.x * 256 + threadIdx.x;   // 43008 float4s = 336*512 floats
    float4 s = part[idx];
#pragma unroll
    for (int q = 1; q < KSLABS; ++q) {
        float4 v = part[q * 43008 + idx];
        s.x += v.x; s.y += v.y; s.z += v.z; s.w += v.w;
    }
    sums[idx] = s;
}

// ---------------- K4: Gram of folded sums, k-split into 8 partial slabs -----------------
__global__ __launch_bounds__(64) void k4_gram(const float* __restrict__ sums,
                                              float* __restrict__ gpart) {
    int row0 = blockIdx.x * 32, col0 = blockIdx.y * 32, k0 = blockIdx.z * 64;
    __shared__ float A[32 * 66], Bt[32 * 66];
    int t = threadIdx.x;
    int row = t >> 1, kk0 = (t & 1) * 32;
#pragma unroll
    for (int q = 0; q < 8; ++q) {
        int kk = kk0 + q * 4;
        int ra = row0 + row, rb = col0 + row;
        float4 va = (ra < NROW) ? *(const float4*)&sums[(size_t)ra * 512 + k0 + kk]
                                : make_float4(0.f, 0.f, 0.f, 0.f);
        float4 vb = (rb < NROW) ? *(const float4*)&sums[(size_t)rb * 512 + k0 + kk]
                                : make_float4(0.f, 0.f, 0.f, 0.f);
        *(float2*)&A[row * 66 + kk]      = make_float2(va.x, va.y);
        *(float2*)&A[row * 66 + kk + 2]  = make_float2(va.z, va.w);
        *(float2*)&Bt[row * 66 + kk]     = make_float2(vb.x, vb.y);
        *(float2*)&Bt[row * 66 + kk + 2] = make_float2(vb.z, vb.w);
    }
    __syncthreads();
    int ty = t >> 3, tx = t & 7;
    float acc[4][4] = {};
    for (int kk = 0; kk < 64; kk += 2) {
        float2 a[4], bb[4];
#pragma unroll
        for (int u = 0; u < 4; ++u) {
            a[u]  = *(const float2*)&A[(ty * 4 + u) * 66 + kk];
            bb[u] = *(const float2*)&Bt[(tx * 4 + u) * 66 + kk];
        }
#pragma unroll
        for (int u = 0; u < 4; ++u)
#pragma unroll
            for (int v = 0; v < 4; ++v)
                acc[u][v] += a[u].x * bb[v].x + a[u].y * bb[v].y;
    }
    float* gp = gpart + (size_t)blockIdx.z * N2;
#pragma unroll
    for (int u = 0; u < 4; ++u) {
        int r1 = row0 + ty * 4 + u;
        if (r1 >= NROW) continue;
        int r2 = col0 + tx * 4;
        if (r2 + 3 < NROW) {
            *(float4*)&gp[(size_t)r1 * NROW + r2] =
                make_float4(acc[u][0], acc[u][1], acc[u][2], acc[u][3]);
        } else {
#pragma unroll
            for (int v = 0; v < 4; ++v)
                if (r2 + v < NROW) gp[(size_t)r1 * NROW + r2 + v] = acc[u][v];
        }
    }
}

// ---------------- K5: per-class masked LSE loss, single pass ----------------------------
__global__ __launch_bounds__(1024) void k5_loss(const float* __restrict__ gpart,
                                                const int* __restrict__ countsPart,
                                                float* __restrict__ out) {
    int c = blockIdx.x, t = threadIdx.x;
    int wv = t >> 6, lane = t & 63;
    __shared__ float invnL[NROW];
    __shared__ uint8_t presL[NROW];
    __shared__ float redE[16], redD[16], redL[16];

    for (int r = t; r < NROW; r += 1024) {
        float ss = 0.0f;
#pragma unroll
        for (int s = 0; s < 8; ++s) ss += gpart[(size_t)s * N2 + (size_t)r * 337];
        invnL[r] = 1.0f / fmaxf(sqrtf(ss), 1e-12f);
        int img = r & 15, cls = r >> 4;
        int cnt = 0;
#pragma unroll
        for (int s = 0; s < 16; ++s) cnt += countsPart[(img * 16 + s) * NUM_C + cls];
        presL[r] = cnt > 0 ? 1 : 0;
    }
    __syncthreads();

    int nc = 0;
#pragma unroll
    for (int j = 0; j < 16; ++j) nc += presL[c * 16 + j];
    if (nc == 0) return;   // class absent in all images: contributes 0 (uniform exit)

    float eS = 0.0f, dE = 0.0f, dL = 0.0f;
    for (int idx = t; idx < 16 * NROW; idx += 1024) {
        int i = idx / NROW, r2 = idx - i * NROW;
        int r1 = c * 16 + i;
        float g = 0.0f;
#pragma unroll
        for (int s = 0; s < 8; ++s) g += gpart[(size_t)s * N2 + (size_t)r1 * NROW + r2];
        if (presL[r1] && presL[r2]) {
            float sv = g * invnL[r1] * invnL[r2] * 10.0f;   // /T, T=0.1
            float e = expf(sv - 10.0f);
            eS += e;
            if ((r2 >> 4) == c) { dE += e; dL += sv; }      // diag block (appears twice)
        }
    }
#pragma unroll
    for (int off = 32; off >= 1; off >>= 1) {
        eS += __shfl_xor(eS, off, 64);
        dE += __shfl_xor(dE, off, 64);
        dL += __shfl_xor(dL, off, 64);
    }
    if (lane == 0) { redE[wv] = eS; redD[wv] = dE; redL[wv] = dL; }
    __syncthreads();
    if (t == 0) {
        float E = 0, D = 0, Ln = 0;
#pragma unroll
        for (int w = 0; w < 16; ++w) { E += redE[w]; D += redD[w]; Ln += redL[w]; }
        float lse = 10.0f + logf(E + D);
        float posMean = Ln / (float)(nc * nc);
        atomicAdd(out, lse - posMean);
    }
}

// ---------------- launcher --------------------------------------------------------------
extern "C" void kernel_launch(void* const* d_in, const int* in_sizes, int n_in,
                              void* d_out, int out_size, void* d_ws, size_t ws_size,
                              hipStream_t stream) {
    const float* features = (const float*)d_in[0];
    const int* labels = (const int*)d_in[1];
    char* ws = (char*)d_ws;

    uint8_t* lab     = (uint8_t*)ws;                               // 65536 B
    int* countsPart  = (int*)(ws + 65536);                         // 21504 B
    float* sums_part = (float*)(ws + 87040);                       // 32*336*512*4 = 22020096 B
    float* sums      = (float*)(ws + 87040 + 22020096);            // 688128 B
    float* gpart     = (float*)(ws + 87040 + 22020096 + 688128);   // 3612672 B
    float* out       = (float*)d_out;

    k1_resize_hist<<<256, 256, 0, stream>>>(labels, lab, countsPart, out);
    k2_sums<<<2048, 256, 0, stream>>>(features, lab, sums_part);
    k3_fold<<<168, 256, 0, stream>>>((const float4*)sums_part, (float4*)sums);
    k4_gram<<<dim3(11, 11, 8), 64, 0, stream>>>(sums, gpart);
    k5_loss<<<21, 1024, 0, stream>>>(gpart, countsPart, out);
}

// Round 7
// 217.709 us; speedup vs baseline: 1.2455x; 1.1183x over previous
//
#include <hip/hip_runtime.h>
#include <cstdint>
#include <cstddef>

#define NUM_C 21
#define NROW 336      // 21 classes * 16 images, row r = cls*16 + img
#define N2   (NROW * NROW)
#define KSLABS 16     // k2: 4 K-quarters x 4 waves -> 16 partial slabs

typedef __attribute__((ext_vector_type(8))) short short8;   // 8 bf16 = 4 VGPRs (MFMA A/B frag)
typedef __attribute__((ext_vector_type(4))) float f32x4;
typedef __attribute__((ext_vector_type(16))) float f32x16;  // 32x32 MFMA C/D frag
typedef __attribute__((ext_vector_type(4))) int int4v;

union frag_u { int4v i; short8 s; };
__device__ __forceinline__ short8 mk_frag(uint32_t a0, uint32_t a1, uint32_t a2, uint32_t a3) {
    frag_u u; u.i = int4v{(int)a0, (int)a1, (int)a2, (int)a3}; return u.s;
}
// packed bf16x2 one-hot: low16 = (eL==c), high16 = (eH==c), value 1.0bf16/0
__device__ __forceinline__ uint32_t mask_pair(uint32_t eL, uint32_t eH, uint32_t c) {
    return (eL == c ? 0x3F80u : 0u) | (eH == c ? 0x3F800000u : 0u);
}
// async global->LDS, 16B/lane (1KB/wave burst), aux=2 (nt: no-allocate, keeps round-4's
// anti-poison-writeback win). dst must be wave-uniform; HW writes dst + lane*16.
__device__ __forceinline__ void load_lds16(const float* src, float* dst) {
    __builtin_amdgcn_global_load_lds((const __attribute__((address_space(1))) void*)src,
                                     (__attribute__((address_space(3))) void*)dst, 16, 0, 2);
}

// ---------------- K1: bilinear label resize (513x513 -> 64x64) + per-block histogram ----
__global__ __launch_bounds__(256) void k1_resize_hist(const int* __restrict__ labels,
                                                      uint8_t* __restrict__ lab,
                                                      int* __restrict__ countsPart,
                                                      float* __restrict__ out) {
    int b = blockIdx.x >> 4, strip = blockIdx.x & 15;
    if (blockIdx.x == 0 && threadIdx.x == 0) out[0] = 0.0f;  // K5 (later in stream) accumulates
    __shared__ int hist[NUM_C];
    if (threadIdx.x < NUM_C) hist[threadIdx.x] = 0;
    __syncthreads();

    int p = strip * 256 + threadIdx.x;      // pixel in [0,4096)
    int y = p >> 6, x = p & 63;
    const int* L = labels + (size_t)b * 263169;   // 513*513
    // sample_f = (i+0.5)*513/64 - 0.5 ; 513/64 = 8.015625 exact in fp32; range [3.5,508.5] -> no clamp
    float sy = (y + 0.5f) * 8.015625f - 0.5f;
    float sx = (x + 0.5f) * 8.015625f - 0.5f;
    int y0 = (int)sy; float fy = sy - (float)y0;
    int x0 = (int)sx; float fx = sx - (float)x0;
    const int* r0 = L + y0 * 513 + x0;
    float L00 = (float)__builtin_nontemporal_load(r0);
    float L01 = (float)__builtin_nontemporal_load(r0 + 1);
    float L10 = (float)__builtin_nontemporal_load(r0 + 513);
    float L11 = (float)__builtin_nontemporal_load(r0 + 514);
    float v0 = (1.0f - fx) * L00 + fx * L01;
    float v1 = (1.0f - fx) * L10 + fx * L11;
    float val = (1.0f - fy) * v0 + fy * v1;
    int c = (int)val;
    lab[b * 4096 + p] = (uint8_t)c;
    atomicAdd(&hist[c], 1);
    __syncthreads();
    if (threadIdx.x < NUM_C) countsPart[blockIdx.x * NUM_C + threadIdx.x] = hist[threadIdx.x];
}

// ---------------- K2: masked pooling, GLOBAL_LOAD_LDS-staged 32x32x16 MFMA GEMM ---------
// Rounds 0-6 lesson: with lane=d (forced by MFMA B-layout), direct global fragment loads
// gather 32 lines strided 16KB per instruction behind a dependent VALU pack tail ->
// latency-bound at 48-84us regardless of scheduling. Fix: decouple via LDS.
//  - Stage [32 d][256 px] fp32 tile with async global_load_lds width=16: each row = ONE
//    contiguous 1KB wave burst (8 instrs/wave, vmcnt-queued, no VGPR round-trip). nt aux.
//  - LDS row stride 260 floats (1040B): ds_read of 32 rows at common k-offset -> 4-way
//    bank aliasing only (1.58x on 8 ds_read_b128/wave/slab -- negligible).
//  - 4 waves K-split the slab (64 px each): conversion VALU per SIMD ~1.3K cyc vs ~13K
//    cyc stream time per slab round -> memory-bound at last.
//  - grid 1024 = (b16 x dg16 x ks4) = exactly 4 blocks/CU (LDS 130KB/CU); no min-waves
//    bound (round-6's (256,8) likely spilled). Single buffer; inter-block overlap hides
//    the stage barrier.
// Layouts (verified r5/r6, absmax 0.0): A row = lane&31 (=class, >=21 auto-zero),
// B col = lane&31 (=d), k = g*8+j; C/D col = lane&31, row = (j&3)+8*(j>>2)+4*g.
// fp32 -> bf16 hi + exact-residual lo, fp32 accumulate.
__global__ __launch_bounds__(256) void k2_sums(const float* __restrict__ feat,
                                               const uint8_t* __restrict__ lab,
                                               float* __restrict__ sums_part) {
    int bid = blockIdx.x;                 // 1024 = b(16) x dg(16) x ks(4)
    int b = bid >> 6, dg = (bid >> 2) & 15, ks = bid & 3;
    int t = threadIdx.x, wv = t >> 6, lane = t & 63;
    int g = lane >> 5;                    // k-group (0,1)
    uint32_t c = lane & 31;               // A row = class (>=21 -> mask always 0)
    __shared__ float tile[32 * 260];      // [32 d][256 px], row stride 260 f (1040 B)

    const float* fbase = feat + ((size_t)(b * 512 + dg * 32)) * 4096 + ks * 1024;
    const uint8_t* lbase = lab + b * 4096 + ks * 1024;

    f32x16 acc;
#pragma unroll
    for (int j = 0; j < 16; ++j) acc[j] = 0.0f;

    for (int slab = 0; slab < 4; ++slab) {
        int px0 = slab * 256;
        // stage: wave wv loads rows wv*8..wv*8+7, one 1KB burst each (async)
#pragma unroll
        for (int rr = 0; rr < 8; ++rr) {
            int r = wv * 8 + rr;
            load_lds16(fbase + (size_t)r * 4096 + px0 + lane * 4, &tile[r * 260]);
        }
        __syncthreads();   // compiler inserts s_waitcnt vmcnt(0) before s_barrier

        // compute: this wave's K-range = px [px0 + wv*64, +64), 4 chunks of 16 px
        const uint8_t* lp = lbase + px0 + wv * 64 + g * 8;
        const float* lrow = &tile[(lane & 31) * 260 + wv * 64 + g * 8];
#pragma unroll
        for (int ch = 0; ch < 4; ++ch) {
            f32x4 fA = *(const f32x4*)(lrow + ch * 16);       // ds_read_b128 x2
            f32x4 fB = *(const f32x4*)(lrow + ch * 16 + 4);
            uint2 wl = *(const uint2*)(lp + ch * 16);         // wave-uniform per g-group

            uint32_t u0 = __float_as_uint(fA[0]), u1 = __float_as_uint(fA[1]),
                     u2 = __float_as_uint(fA[2]), u3 = __float_as_uint(fA[3]),
                     u4 = __float_as_uint(fB[0]), u5 = __float_as_uint(fB[1]),
                     u6 = __float_as_uint(fB[2]), u7 = __float_as_uint(fB[3]);
            // hi = truncate-to-bf16: pack high16 of consecutive floats (1 v_perm/pair)
            short8 bHi = mk_frag(__builtin_amdgcn_perm(u1, u0, 0x07060302u),
                                 __builtin_amdgcn_perm(u3, u2, 0x07060302u),
                                 __builtin_amdgcn_perm(u5, u4, 0x07060302u),
                                 __builtin_amdgcn_perm(u7, u6, 0x07060302u));
            // lo = truncate-to-bf16 of exact residual f - hi (shared exponent -> exact)
            float t0 = fA[0] - __uint_as_float(u0 & 0xFFFF0000u);
            float t1 = fA[1] - __uint_as_float(u1 & 0xFFFF0000u);
            float t2 = fA[2] - __uint_as_float(u2 & 0xFFFF0000u);
            float t3 = fA[3] - __uint_as_float(u3 & 0xFFFF0000u);
            float t4 = fB[0] - __uint_as_float(u4 & 0xFFFF0000u);
            float t5 = fB[1] - __uint_as_float(u5 & 0xFFFF0000u);
            float t6 = fB[2] - __uint_as_float(u6 & 0xFFFF0000u);
            float t7 = fB[3] - __uint_as_float(u7 & 0xFFFF0000u);
            short8 bLo = mk_frag(
                __builtin_amdgcn_perm(__float_as_uint(t1), __float_as_uint(t0), 0x07060302u),
                __builtin_amdgcn_perm(__float_as_uint(t3), __float_as_uint(t2), 0x07060302u),
                __builtin_amdgcn_perm(__float_as_uint(t5), __float_as_uint(t4), 0x07060302u),
                __builtin_amdgcn_perm(__float_as_uint(t7), __float_as_uint(t6), 0x07060302u));

            uint32_t e0 = wl.x & 255u, e1 = (wl.x >> 8) & 255u,
                     e2 = (wl.x >> 16) & 255u, e3 = wl.x >> 24;
            uint32_t e4 = wl.y & 255u, e5 = (wl.y >> 8) & 255u,
                     e6 = (wl.y >> 16) & 255u, e7 = wl.y >> 24;
            short8 a = mk_frag(mask_pair(e0, e1, c), mask_pair(e2, e3, c),
                               mask_pair(e4, e5, c), mask_pair(e6, e7, c));

            acc = __builtin_amdgcn_mfma_f32_32x32x16_bf16(a, bHi, acc, 0, 0, 0);
            acc = __builtin_amdgcn_mfma_f32_32x32x16_bf16(a, bLo, acc, 0, 0, 0);
        }
        __syncthreads();   // before next slab overwrites the tile
    }

    // C/D: col = lane&31 (=d), row = (j&3) + 8*(j>>2) + 4*g (=class).
    // Per (j): 32 lanes write 128B consecutive -> coalesced.
    float* sp = sums_part + (size_t)(ks * 4 + wv) * NROW * 512;
    int d = dg * 32 + (lane & 31);
    int rb = 4 * g;
#pragma unroll
    for (int j = 0; j < 16; ++j) {
        int row = (j & 3) + 8 * (j >> 2) + rb;
        if (row < NUM_C) sp[(size_t)(row * 16 + b) * 512 + d] = acc[j];
    }
}

// ---------------- K3: fold 16 partial slabs -> sums[336][512] ---------------------------
// Reads its own just-written 11MB (L2/L3-warm): keep cached loads.
__global__ __launch_bounds__(256) void k3_fold(const float4* __restrict__ part,
                                               float4* __restrict__ sums) {
    int idx = blockIdx.x * 256 + threadIdx.x;   // 43008 float4s = 336*512 floats
    float4 s = part[idx];
#pragma unroll
    for (int q = 1; q < KSLABS; ++q) {
        float4 v = part[q * 43008 + idx];
        s.x += v.x; s.y += v.y; s.z += v.z; s.w += v.w;
    }
    sums[idx] = s;
}

// ---------------- K4: Gram of folded sums, k-split into 8 partial slabs -----------------
__global__ __launch_bounds__(64) void k4_gram(const float* __restrict__ sums,
                                              float* __restrict__ gpart) {
    int row0 = blockIdx.x * 32, col0 = blockIdx.y * 32, k0 = blockIdx.z * 64;
    __shared__ float A[32 * 66], Bt[32 * 66];
    int t = threadIdx.x;
    int row = t >> 1, kk0 = (t & 1) * 32;
#pragma unroll
    for (int q = 0; q < 8; ++q) {
        int kk = kk0 + q * 4;
        int ra = row0 + row, rb = col0 + row;
        float4 va = (ra < NROW) ? *(const float4*)&sums[(size_t)ra * 512 + k0 + kk]
                                : make_float4(0.f, 0.f, 0.f, 0.f);
        float4 vb = (rb < NROW) ? *(const float4*)&sums[(size_t)rb * 512 + k0 + kk]
                                : make_float4(0.f, 0.f, 0.f, 0.f);
        *(float2*)&A[row * 66 + kk]      = make_float2(va.x, va.y);
        *(float2*)&A[row * 66 + kk + 2]  = make_float2(va.z, va.w);
        *(float2*)&Bt[row * 66 + kk]     = make_float2(vb.x, vb.y);
        *(float2*)&Bt[row * 66 + kk + 2] = make_float2(vb.z, vb.w);
    }
    __syncthreads();
    int ty = t >> 3, tx = t & 7;
    float acc[4][4] = {};
    for (int kk = 0; kk < 64; kk += 2) {
        float2 a[4], bb[4];
#pragma unroll
        for (int u = 0; u < 4; ++u) {
            a[u]  = *(const float2*)&A[(ty * 4 + u) * 66 + kk];
            bb[u] = *(const float2*)&Bt[(tx * 4 + u) * 66 + kk];
        }
#pragma unroll
        for (int u = 0; u < 4; ++u)
#pragma unroll
            for (int v = 0; v < 4; ++v)
                acc[u][v] += a[u].x * bb[v].x + a[u].y * bb[v].y;
    }
    float* gp = gpart + (size_t)blockIdx.z * N2;
#pragma unroll
    for (int u = 0; u < 4; ++u) {
        int r1 = row0 + ty * 4 + u;
        if (r1 >= NROW) continue;
        int r2 = col0 + tx * 4;
        if (r2 + 3 < NROW) {
            *(float4*)&gp[(size_t)r1 * NROW + r2] =
                make_float4(acc[u][0], acc[u][1], acc[u][2], acc[u][3]);
        } else {
#pragma unroll
            for (int v = 0; v < 4; ++v)
                if (r2 + v < NROW) gp[(size_t)r1 * NROW + r2 + v] = acc[u][v];
        }
    }
}

// ---------------- K5: per-class masked LSE loss, single pass ----------------------------
__global__ __launch_bounds__(1024) void k5_loss(const float* __restrict__ gpart,
                                                const int* __restrict__ countsPart,
                                                float* __restrict__ out) {
    int c = blockIdx.x, t = threadIdx.x;
    int wv = t >> 6, lane = t & 63;
    __shared__ float invnL[NROW];
    __shared__ uint8_t presL[NROW];
    __shared__ float redE[16], redD[16], redL[16];

    for (int r = t; r < NROW; r += 1024) {
        float ss = 0.0f;
#pragma unroll
        for (int s = 0; s < 8; ++s) ss += gpart[(size_t)s * N2 + (size_t)r * 337];
        invnL[r] = 1.0f / fmaxf(sqrtf(ss), 1e-12f);
        int img = r & 15, cls = r >> 4;
        int cnt = 0;
#pragma unroll
        for (int s = 0; s < 16; ++s) cnt += countsPart[(img * 16 + s) * NUM_C + cls];
        presL[r] = cnt > 0 ? 1 : 0;
    }
    __syncthreads();

    int nc = 0;
#pragma unroll
    for (int j = 0; j < 16; ++j) nc += presL[c * 16 + j];
    if (nc == 0) return;   // class absent in all images: contributes 0 (uniform exit)

    float eS = 0.0f, dE = 0.0f, dL = 0.0f;
    for (int idx = t; idx < 16 * NROW; idx += 1024) {
        int i = idx / NROW, r2 = idx - i * NROW;
        int r1 = c * 16 + i;
        float g = 0.0f;
#pragma unroll
        for (int s = 0; s < 8; ++s) g += gpart[(size_t)s * N2 + (size_t)r1 * NROW + r2];
        if (presL[r1] && presL[r2]) {
            float sv = g * invnL[r1] * invnL[r2] * 10.0f;   // /T, T=0.1
            float e = expf(sv - 10.0f);
            eS += e;
            if ((r2 >> 4) == c) { dE += e; dL += sv; }      // diag block (appears twice)
        }
    }
#pragma unroll
    for (int off = 32; off >= 1; off >>= 1) {
        eS += __shfl_xor(eS, off, 64);
        dE += __shfl_xor(dE, off, 64);
        dL += __shfl_xor(dL, off, 64);
    }
    if (lane == 0) { redE[wv] = eS; redD[wv] = dE; redL[wv] = dL; }
    __syncthreads();
    if (t == 0) {
        float E = 0, D = 0, Ln = 0;
#pragma unroll
        for (int w = 0; w < 16; ++w) { E += redE[w]; D += redD[w]; Ln += redL[w]; }
        float lse = 10.0f + logf(E + D);
        float posMean = Ln / (float)(nc * nc);
        atomicAdd(out, lse - posMean);
    }
}

// ---------------- launcher --------------------------------------------------------------
extern "C" void kernel_launch(void* const* d_in, const int* in_sizes, int n_in,
                              void* d_out, int out_size, void* d_ws, size_t ws_size,
                              hipStream_t stream) {
    const float* features = (const float*)d_in[0];
    const int* labels = (const int*)d_in[1];
    char* ws = (char*)d_ws;

    uint8_t* lab     = (uint8_t*)ws;                               // 65536 B
    int* countsPart  = (int*)(ws + 65536);                         // 21504 B
    float* sums_part = (float*)(ws + 87040);                       // 16*336*512*4 = 11010048 B
    float* sums      = (float*)(ws + 87040 + 11010048);            // 688128 B
    float* gpart     = (float*)(ws + 87040 + 11010048 + 688128);   // 3612672 B
    float* out       = (float*)d_out;

    k1_resize_hist<<<256, 256, 0, stream>>>(labels, lab, countsPart, out);
    k2_sums<<<1024, 256, 0, stream>>>(features, lab, sums_part);
    k3_fold<<<168, 256, 0, stream>>>((const float4*)sums_part, (float4*)sums);
    k4_gram<<<dim3(11, 11, 8), 64, 0, stream>>>(sums, gpart);
    k5_loss<<<21, 1024, 0, stream>>>(gpart, countsPart, out);
}